// Round 10
// baseline (1189.847 us; speedup 1.0000x reference)
//
#include <hip/hip_runtime.h>
#include <hip/hip_bf16.h>
#include <math.h>

#define HW 4096
#define LN_EPS 1e-5f

typedef _Float16 half4v __attribute__((ext_vector_type(4)));
typedef _Float16 half8v __attribute__((ext_vector_type(8)));
typedef float float4v __attribute__((ext_vector_type(4)));
typedef __fp16 fp16v2 __attribute__((ext_vector_type(2)));

#if __has_builtin(__builtin_amdgcn_exp2f)
#define EXP2F(x) __builtin_amdgcn_exp2f(x)
#else
#define EXP2F(x) exp2f(x)
#endif

__device__ __forceinline__ half4v lo4(half8v v) { return __builtin_shufflevector(v, v, 0, 1, 2, 3); }
__device__ __forceinline__ half4v hi4(half8v v) { return __builtin_shufflevector(v, v, 4, 5, 6, 7); }

__device__ __forceinline__ void gload_lds16(const _Float16* g, _Float16* l) {
#if __has_builtin(__builtin_amdgcn_global_load_lds)
    __builtin_amdgcn_global_load_lds(
        (const __attribute__((address_space(1))) void*)(const void*)g,
        (__attribute__((address_space(3))) void*)(void*)l, 16, 0, 0);
#else
    int lane = threadIdx.x & 63;
    *(half8v*)(l + lane * 8) = *(const half8v*)g;
#endif
}

struct P {
    const float *x, *wq, *wp, *b_proj, *pb, *gamma, *beta;
    _Float16 *xt, *qa, *ka, *va;
    float *op, *lp, *pos;
    _Float16 *wqh, *wph;
    unsigned int* cnt; // [0..7] epoch0, [8..15] epoch1, [16..47] qcnt
    float* out;
};

// fast grid barrier: 8 spread counters per epoch, thread-0 arrival+poll
__device__ __forceinline__ void gbarrier(unsigned int* base, int t) {
    __syncthreads();
    if (t == 0) {
        __threadfence();
        __hip_atomic_fetch_add(base + (blockIdx.x & 7), 1u, __ATOMIC_RELEASE,
                               __HIP_MEMORY_SCOPE_AGENT);
        while (true) {
            unsigned int sum = 0;
            #pragma unroll
            for (int i = 0; i < 8; i++)
                sum += __hip_atomic_load(base + i, __ATOMIC_ACQUIRE, __HIP_MEMORY_SCOPE_AGENT);
            if (sum == 1024u) break;
            __builtin_amdgcn_s_sleep(16);
        }
    }
    __syncthreads();
}

// ---------------- phase A: x transpose + weight convert + pos bilinear (896 units) -----
__device__ __forceinline__ void phaseA(int u, int t, char* smem, const P& pp) {
    int w = t >> 6, lane = t & 63;
    if (u < 512) { // transpose x [512][4096] f32 -> xt [4096][512] f16
        _Float16 (*tile)[65] = (_Float16(*)[65])smem;
        int c0 = (u >> 6) * 64, p0 = (u & 63) * 64;
        #pragma unroll
        for (int r = 0; r < 16; r++)
            tile[w * 16 + r][lane] = (_Float16)pp.x[(c0 + w * 16 + r) * HW + p0 + lane];
        __syncthreads();
        int cgx = (t & 15) * 4, pr = t >> 4;
        #pragma unroll
        for (int r = 0; r < 4; r++) {
            int p = pr + r * 16;
            half4v v;
            #pragma unroll
            for (int k = 0; k < 4; k++) v[k] = tile[cgx + k][p];
            *(half4v*)&pp.xt[(p0 + p) * 512 + c0 + cgx] = v;
        }
        return;
    }
    int i = (u - 512) * 256 + t;
    const float qs = 0.17677669529663687f * 1.4426950408889634f; // scale * log2(e)
    if (i < 49152) { // wq, Q rows pre-scaled
        float s = (i < 16384) ? qs : 1.0f;
        float4v a = *(const float4v*)(pp.wq + i * 8);
        float4v b = *(const float4v*)(pp.wq + i * 8 + 4);
        half8v h;
        #pragma unroll
        for (int k = 0; k < 4; k++) { h[k] = (_Float16)(a[k] * s); h[4 + k] = (_Float16)(b[k] * s); }
        *(half8v*)(pp.wqh + i * 8) = h;
    } else if (i < 65536) { // wp
        int j = i - 49152;
        float4v a = *(const float4v*)(pp.wp + j * 8);
        float4v b = *(const float4v*)(pp.wp + j * 8 + 4);
        half8v h;
        #pragma unroll
        for (int k = 0; k < 4; k++) { h[k] = (_Float16)a[k]; h[4 + k] = (_Float16)b[k]; }
        *(half8v*)(pp.wph + j * 8) = h;
    } else { // pos bilinear 16->64, times log2(e)
        int j = i - 65536;
        int h = j >> 12, p = j & 4095, y = p >> 6, xx = p & 63;
        float sy = y * 0.25f - 0.375f, sx = xx * 0.25f - 0.375f;
        float fy = floorf(sy), fx = floorf(sx);
        float wy = sy - fy, wx = sx - fx;
        int y0 = (int)fy, x0 = (int)fx;
        int y1 = y0 + 1 < 15 ? y0 + 1 : 15;
        int x1 = x0 + 1 < 15 ? x0 + 1 : 15;
        y0 = y0 > 0 ? y0 : 0;
        x0 = x0 > 0 ? x0 : 0;
        const float* src = pp.pb + h * 256;
        float v = (1.f - wy) * ((1.f - wx) * src[y0 * 16 + x0] + wx * src[y0 * 16 + x1]) +
                  wy * ((1.f - wx) * src[y1 * 16 + x0] + wx * src[y1 * 16 + x1]);
        pp.pos[j] = v * 1.4426950408889634f;
    }
}

// ---------------- phase B: QKV GEMM, 768 units of 64n x 64p ----------------------------
__device__ __forceinline__ void phaseB(int u, int t, const P& pp) {
    int w = t >> 6, lane = t & 63, quad = lane >> 4, l16 = lane & 15;
    int n0 = (u >> 6) * 64;
    int p0 = (u & 63) * 64;
    const _Float16* aptr = pp.xt + (p0 + w * 16 + l16) * 512 + quad * 8;
    const _Float16* bptr = pp.wqh + (n0 + l16) * 512 + quad * 8;
    float4v acc[4] = {};
    #pragma unroll 4
    for (int kc = 0; kc < 16; kc++) {
        half8v a = *(const half8v*)(aptr + kc * 32);
        #pragma unroll
        for (int nt = 0; nt < 4; nt++) {
            half8v b = *(const half8v*)(bptr + nt * 16 * 512 + kc * 32);
            acc[nt] = __builtin_amdgcn_mfma_f32_16x16x32_f16(a, b, acc[nt], 0, 0, 0);
        }
    }
    #pragma unroll
    for (int nt = 0; nt < 4; nt++) {
        int o = n0 + nt * 16 + l16;
        #pragma unroll
        for (int r = 0; r < 4; r++) {
            int p = p0 + w * 16 + quad * 4 + r;
            _Float16 v = (_Float16)acc[nt][r];
            if (o < 256) {
                pp.qa[(o >> 5) * 131072 + p * 32 + (o & 31)] = v;
            } else if (o < 512) {
                int oc = o - 256, hh = oc >> 5, d = oc & 31;
                pp.ka[hh * 131072 + (p >> 4) * 512 + ((d >> 3) * 16 + (p & 15)) * 8 + (d & 7)] = v;
            } else {
                int oc = o - 512, hh = oc >> 5, d = oc & 31;
                pp.va[hh * 131072 + (p >> 4) * 512 + (((p >> 2) & 3) * 16 + (d & 15)) * 8 +
                      (d >> 4) * 4 + (p & 3)] = v;
            }
        }
    }
}

// ---------------- phase C: attention, 1024 units (8h x 4jq x 32qb) ---------------------
__device__ __forceinline__ void phaseC(int u, int t, char* smem, const P& pp) {
    _Float16* kbuf = (_Float16*)smem;            // 2 x 2048
    _Float16* vbuf = (_Float16*)(smem + 8192);   // 2 x 2048
    float* posl = (float*)(smem + 16384);        // 1024
    int w = t >> 6, lane = t & 63, quad = lane >> 4, l16 = lane & 15;
    int h = u & 7;
    int jq = (u >> 3) & 3;
    int qb = u >> 5;
    int q0 = qb * 128 + w * 32;
    float* opp = pp.op + jq * 1048576;
    float* lpp = pp.lp + jq * 32768;

    *(float4v*)(posl + t * 4) = *(const float4v*)(pp.pos + h * HW + jq * 1024 + t * 4);

    half8v qf0 = *(const half8v*)(pp.qa + h * 131072 + (q0 + l16) * 32 + quad * 8);
    half8v qf1 = *(const half8v*)(pp.qa + h * 131072 + (q0 + 16 + l16) * 32 + quad * 8);

    const _Float16* kg = pp.ka + h * 131072 + jq * 32768;
    const _Float16* vg = pp.va + h * 131072 + jq * 32768;

    gload_lds16(kg + (w * 64 + lane) * 8, kbuf + w * 512);
    gload_lds16(vg + (w * 64 + lane) * 8, vbuf + w * 512);

    float4v o00 = {}, o01 = {}, o10 = {}, o11 = {};
    float lsum0 = 0.f, lsum1 = 0.f;
    const fp16v2 one2 = {(__fp16)1.0f, (__fp16)1.0f};

    for (int tile = 0; tile < 16; tile++) {
        int buf = tile & 1;
        __syncthreads();
        if (tile + 1 < 16) {
            gload_lds16(kg + (tile + 1) * 2048 + (w * 64 + lane) * 8,
                        kbuf + (buf ^ 1) * 2048 + w * 512);
            gload_lds16(vg + (tile + 1) * 2048 + (w * 64 + lane) * 8,
                        vbuf + (buf ^ 1) * 2048 + w * 512);
        }
        #pragma unroll
        for (int w16 = 0; w16 < 4; w16++) {
            half8v kf = *(const half8v*)(kbuf + buf * 2048 + w16 * 512 + lane * 8);
            half8v vf = *(const half8v*)(vbuf + buf * 2048 + w16 * 512 + lane * 8);
            float4v pbv = *(const float4v*)(posl + tile * 64 + w16 * 16 + quad * 4);

            float4v s0 = __builtin_amdgcn_mfma_f32_16x16x32_f16(kf, qf0, pbv, 0, 0, 0);
            float4v s1 = __builtin_amdgcn_mfma_f32_16x16x32_f16(kf, qf1, pbv, 0, 0, 0);

            float e0 = EXP2F(s0[0]);
            float e1 = EXP2F(s0[1]);
            float e2 = EXP2F(s0[2]);
            float e3 = EXP2F(s0[3]);
            float f0 = EXP2F(s1[0]);
            float f1 = EXP2F(s1[1]);
            float f2 = EXP2F(s1[2]);
            float f3 = EXP2F(s1[3]);

            fp16v2 a01 = __builtin_amdgcn_cvt_pkrtz(e0, e1);
            fp16v2 a23 = __builtin_amdgcn_cvt_pkrtz(e2, e3);
            fp16v2 b01 = __builtin_amdgcn_cvt_pkrtz(f0, f1);
            fp16v2 b23 = __builtin_amdgcn_cvt_pkrtz(f2, f3);
            half4v pa0 = __builtin_bit_cast(half4v, __builtin_shufflevector(a01, a23, 0, 1, 2, 3));
            half4v pa1 = __builtin_bit_cast(half4v, __builtin_shufflevector(b01, b23, 0, 1, 2, 3));

#if __has_builtin(__builtin_amdgcn_fdot2)
            lsum0 = __builtin_amdgcn_fdot2(a01, one2, lsum0, false);
            lsum0 = __builtin_amdgcn_fdot2(a23, one2, lsum0, false);
            lsum1 = __builtin_amdgcn_fdot2(b01, one2, lsum1, false);
            lsum1 = __builtin_amdgcn_fdot2(b23, one2, lsum1, false);
#else
            lsum0 += (e0 + e1) + (e2 + e3);
            lsum1 += (f0 + f1) + (f2 + f3);
#endif
            o00 = __builtin_amdgcn_mfma_f32_16x16x16f16(pa0, lo4(vf), o00, 0, 0, 0);
            o01 = __builtin_amdgcn_mfma_f32_16x16x16f16(pa0, hi4(vf), o01, 0, 0, 0);
            o10 = __builtin_amdgcn_mfma_f32_16x16x16f16(pa1, lo4(vf), o10, 0, 0, 0);
            o11 = __builtin_amdgcn_mfma_f32_16x16x16f16(pa1, hi4(vf), o11, 0, 0, 0);
        }
    }
    lsum0 += __shfl_xor(lsum0, 16, 64);
    lsum0 += __shfl_xor(lsum0, 32, 64);
    lsum1 += __shfl_xor(lsum1, 16, 64);
    lsum1 += __shfl_xor(lsum1, 32, 64);
    #pragma unroll
    for (int r = 0; r < 4; r++) {
        int qr = quad * 4 + r;
        int qi0 = q0 + qr, qi1 = q0 + 16 + qr;
        opp[qi0 * 256 + h * 32 + l16] = o00[r];
        opp[qi0 * 256 + h * 32 + 16 + l16] = o01[r];
        opp[qi1 * 256 + h * 32 + l16] = o10[r];
        opp[qi1 * 256 + h * 32 + 16 + l16] = o11[r];
    }
    if (quad == 0) {
        lpp[(q0 + l16) * 8 + h] = lsum0;
        lpp[(q0 + 16 + l16) * 8 + h] = lsum1;
    }
}

// ---------------- phase D: combine + proj GEMM + residual + LayerNorm (16-pos tile) ----
__device__ __forceinline__ void phaseD(int u, int t, char* smem, const P& pp) {
    _Float16* ys = (_Float16*)smem;                        // 16 x 264
    float (*red)[4][16] = (float(*)[4][16])(smem + 8448);  // [2][4][16]
    int w = t >> 6, lane = t & 63, quad = lane >> 4, l16 = lane & 15;
    int p0 = u * 16;
    #pragma unroll
    for (int g4 = 0; g4 < 4; g4++) {
        int g = t + g4 * 256;
        int p = g >> 6, cgx = (g & 63) * 4;
        int pi = p0 + p;
        float4v a0 = *(const float4v*)(pp.op + pi * 256 + cgx);
        float4v a1 = *(const float4v*)(pp.op + 1048576 + pi * 256 + cgx);
        float4v a2 = *(const float4v*)(pp.op + 2097152 + pi * 256 + cgx);
        float4v a3 = *(const float4v*)(pp.op + 3145728 + pi * 256 + cgx);
        int hh = cgx >> 5;
        float l = pp.lp[pi * 8 + hh] + pp.lp[32768 + pi * 8 + hh] +
                  pp.lp[65536 + pi * 8 + hh] + pp.lp[98304 + pi * 8 + hh];
        float inv = 1.f / l;
        half4v yv;
        #pragma unroll
        for (int k = 0; k < 4; k++) yv[k] = (_Float16)(((a0[k] + a1[k]) + (a2[k] + a3[k])) * inv);
        *(half4v*)(ys + p * 264 + cgx) = yv;
    }
    __syncthreads();
    float4v acc[8] = {};
    #pragma unroll
    for (int kc = 0; kc < 8; kc++) {
        half8v b = *(const half8v*)(ys + l16 * 264 + kc * 32 + quad * 8);
        #pragma unroll
        for (int mt = 0; mt < 8; mt++) {
            half8v a = *(const half8v*)(pp.wph + (w * 128 + mt * 16 + l16) * 256 + kc * 32 + quad * 8);
            acc[mt] = __builtin_amdgcn_mfma_f32_16x16x32_f16(a, b, acc[mt], 0, 0, 0);
        }
    }
    int p = p0 + l16;
    float sum = 0.f, sumsq = 0.f;
    #pragma unroll
    for (int mt = 0; mt < 8; mt++)
        #pragma unroll
        for (int r = 0; r < 4; r++) {
            int c = w * 128 + mt * 16 + quad * 4 + r;
            float v = acc[mt][r] + pp.b_proj[c] + pp.x[c * HW + p];
            acc[mt][r] = v;
            sum += v;
            sumsq += v * v;
        }
    sum += __shfl_xor(sum, 16, 64);
    sum += __shfl_xor(sum, 32, 64);
    sumsq += __shfl_xor(sumsq, 16, 64);
    sumsq += __shfl_xor(sumsq, 32, 64);
    if (quad == 0) { red[0][w][l16] = sum; red[1][w][l16] = sumsq; }
    __syncthreads();
    float s0 = (red[0][0][l16] + red[0][1][l16]) + (red[0][2][l16] + red[0][3][l16]);
    float s1 = (red[1][0][l16] + red[1][1][l16]) + (red[1][2][l16] + red[1][3][l16]);
    float mean = s0 * (1.f / 512.f);
    float var = s1 * (1.f / 512.f) - mean * mean;
    float rstd = rsqrtf(var + LN_EPS);
    #pragma unroll
    for (int mt = 0; mt < 8; mt++)
        #pragma unroll
        for (int r = 0; r < 4; r++) {
            int c = w * 128 + mt * 16 + quad * 4 + r;
            pp.out[c * HW + p] = (acc[mt][r] - mean) * rstd * pp.gamma[c] + pp.beta[c];
        }
}

// ---------------- fused kernel: A -> bar -> B -> bar -> C -> atomic-drain D ------------
__global__ __launch_bounds__(256, 4) void k_fused(P pp) {
    __shared__ __attribute__((aligned(16))) char smem[24576];
    __shared__ int stick;
    int bid = blockIdx.x, t = threadIdx.x;

    if (bid < 896) phaseA(bid, t, smem, pp);
    gbarrier(pp.cnt, t);

    if (bid < 768) phaseB(bid, t, pp);
    gbarrier(pp.cnt + 8, t);

    phaseC(bid, t, smem, pp);

    // drain: 32nd finisher of each 128-query group runs proj+LN for that group
    int qb = bid >> 5;
    __threadfence();
    if (t == 0)
        stick = (int)__hip_atomic_fetch_add(pp.cnt + 16 + qb, 1u, __ATOMIC_ACQ_REL,
                                            __HIP_MEMORY_SCOPE_AGENT);
    __syncthreads();
    if (stick == 31) {
        #pragma unroll 1
        for (int g = 0; g < 8; g++) {
            __syncthreads();
            phaseD(qb * 8 + g, t, smem, pp);
        }
    }
}

extern "C" void kernel_launch(void* const* d_in, const int* in_sizes, int n_in,
                              void* d_out, int out_size, void* d_ws, size_t ws_size,
                              hipStream_t stream) {
    char* ws = (char*)d_ws;
    P pp;
    pp.x      = (const float*)d_in[0];
    pp.wq     = (const float*)d_in[1];
    pp.wp     = (const float*)d_in[2];
    pp.b_proj = (const float*)d_in[3];
    pp.pb     = (const float*)d_in[4];
    pp.gamma  = (const float*)d_in[5];
    pp.beta   = (const float*)d_in[6];
    pp.xt  = (_Float16*)(ws);              // 4194304
    pp.qa  = (_Float16*)(ws + 4194304);    // 2097152
    pp.ka  = (_Float16*)(ws + 6291456);    // 2097152
    pp.va  = (_Float16*)(ws + 8388608);    // 2097152
    pp.op  = (float*)   (ws + 10485760);   // 16777216
    pp.lp  = (float*)   (ws + 27262976);   // 524288
    pp.pos = (float*)   (ws + 27787264);   // 131072
    pp.wqh = (_Float16*)(ws + 27918336);   // 786432
    pp.wph = (_Float16*)(ws + 28704768);   // 262144
    pp.cnt = (unsigned int*)(ws + 28966912); // 48 uints (2 barrier epochs + 32 qcnt)
    pp.out = (float*)d_out;

    hipMemsetAsync((void*)pp.cnt, 0, 256, stream);
    P arg = pp;
    k_fused<<<1024, 256, 0, stream>>>(arg);
}

// Round 11
// 152.114 us; speedup vs baseline: 7.8221x; 7.8221x over previous
//
#include <hip/hip_runtime.h>
#include <hip/hip_bf16.h>
#include <math.h>

#define HW 4096
#define LN_EPS 1e-5f

typedef _Float16 half4v __attribute__((ext_vector_type(4)));
typedef _Float16 half8v __attribute__((ext_vector_type(8)));
typedef float float4v __attribute__((ext_vector_type(4)));
typedef __fp16 fp16v2 __attribute__((ext_vector_type(2)));

#if __has_builtin(__builtin_amdgcn_exp2f)
#define EXP2F(x) __builtin_amdgcn_exp2f(x)
#else
#define EXP2F(x) exp2f(x)
#endif

__device__ __forceinline__ half4v lo4(half8v v) { return __builtin_shufflevector(v, v, 0, 1, 2, 3); }
__device__ __forceinline__ half4v hi4(half8v v) { return __builtin_shufflevector(v, v, 4, 5, 6, 7); }

__device__ __forceinline__ void gload_lds16(const _Float16* g, _Float16* l) {
#if __has_builtin(__builtin_amdgcn_global_load_lds)
    __builtin_amdgcn_global_load_lds(
        (const __attribute__((address_space(1))) void*)(const void*)g,
        (__attribute__((address_space(3))) void*)(void*)l, 16, 0, 0);
#else
    int lane = threadIdx.x & 63;
    *(half8v*)(l + lane * 8) = *(const half8v*)g;
#endif
}

// ---------------- kernel 1: QKV GEMM (self-staging) + wp convert prelude ---------------
// grid 384 = 12 n-tiles x 32 p-tiles (128 pos). Outputs:
//   qa [h][q][d]; ka: [h][j>>4][lane=(d>>3)*16+(j&15)][idx=d&7]
//   va: [h][j>>4][lane=((j>>2)&3)*16+(d&15)][idx=(d>>4)*4+(j&3)]
__global__ __launch_bounds__(256) void k_qkv(const float* __restrict__ x,
                                             const float* __restrict__ wq,
                                             const float* __restrict__ wp,
                                             _Float16* __restrict__ wph,
                                             _Float16* __restrict__ qa,
                                             _Float16* __restrict__ ka,
                                             _Float16* __restrict__ va) {
    __shared__ __attribute__((aligned(16))) _Float16 xs[128][72];
    int bid = blockIdx.x, t = threadIdx.x;
    int w = t >> 6, lane = t & 63, quad = lane >> 4, l16 = lane & 15;
    const float qs = 0.17677669529663687f * 1.4426950408889634f; // scale * log2(e)

    // prelude: first 128 blocks convert wp (512*256 = 128*1024 elems), used 2 kernels later
    if (bid < 128) {
        int i = bid * 1024 + t * 4;
        float4v a = *(const float4v*)(wp + i);
        half4v h;
        #pragma unroll
        for (int k = 0; k < 4; k++) h[k] = (_Float16)a[k];
        *(half4v*)(wph + i) = h;
    }

    int n0 = (bid >> 5) * 64;
    int p0 = (bid & 31) * 128;
    int sp = t & 127;        // staging pos
    int sg = (t >> 7) * 32;  // staging ch half

    float4v acc[2][4] = {};
    for (int k0 = 0; k0 < 512; k0 += 64) {
        __syncthreads();
        #pragma unroll
        for (int cc8 = 0; cc8 < 4; cc8++) {
            int cb = sg + cc8 * 8;
            half8v v;
            #pragma unroll
            for (int c = 0; c < 8; c++) v[c] = (_Float16)x[(k0 + cb + c) * HW + p0 + sp];
            *(half8v*)&xs[sp][cb] = v;
        }
        __syncthreads();
        #pragma unroll
        for (int kc2 = 0; kc2 < 2; kc2++) {
            half8v a0 = *(const half8v*)&xs[w * 16 + l16][kc2 * 32 + quad * 8];
            half8v a1 = *(const half8v*)&xs[64 + w * 16 + l16][kc2 * 32 + quad * 8];
            #pragma unroll
            for (int nt = 0; nt < 4; nt++) {
                float s = (n0 + nt * 16 < 256) ? qs : 1.0f; // uniform per nt-group
                const float* wr = wq + (n0 + nt * 16 + l16) * 512 + k0 + kc2 * 32 + quad * 8;
                float4v b0 = *(const float4v*)wr;
                float4v b1 = *(const float4v*)(wr + 4);
                half8v b;
                #pragma unroll
                for (int k = 0; k < 4; k++) {
                    b[k] = (_Float16)(b0[k] * s);
                    b[4 + k] = (_Float16)(b1[k] * s);
                }
                acc[0][nt] = __builtin_amdgcn_mfma_f32_16x16x32_f16(a0, b, acc[0][nt], 0, 0, 0);
                acc[1][nt] = __builtin_amdgcn_mfma_f32_16x16x32_f16(a1, b, acc[1][nt], 0, 0, 0);
            }
        }
    }
    #pragma unroll
    for (int ps = 0; ps < 2; ps++) {
        #pragma unroll
        for (int nt = 0; nt < 4; nt++) {
            int o = n0 + nt * 16 + l16;
            #pragma unroll
            for (int r = 0; r < 4; r++) {
                int p = p0 + ps * 64 + w * 16 + quad * 4 + r;
                _Float16 v = (_Float16)acc[ps][nt][r];
                if (o < 256) {
                    qa[(o >> 5) * 131072 + p * 32 + (o & 31)] = v;
                } else if (o < 512) {
                    int oc = o - 256, hh = oc >> 5, d = oc & 31;
                    ka[hh * 131072 + (p >> 4) * 512 + ((d >> 3) * 16 + (p & 15)) * 8 + (d & 7)] = v;
                } else {
                    int oc = o - 512, hh = oc >> 5, d = oc & 31;
                    va[hh * 131072 + (p >> 4) * 512 + (((p >> 2) & 3) * 16 + (d & 15)) * 8 +
                       (d >> 4) * 4 + (p & 3)] = v;
                }
            }
        }
    }
}

// ---------------- kernel 2: flash attention, inline pos, async-LDS dbuf, j-split x4 ----
// grid 1024 = 8h x 4jq x 32qb; block = 128 q (4 waves x 32 q).
__global__ __launch_bounds__(256, 4) void k_attn(const _Float16* __restrict__ qa,
                                                 const _Float16* __restrict__ ka,
                                                 const _Float16* __restrict__ va,
                                                 const float* __restrict__ pb,
                                                 float* __restrict__ op,
                                                 float* __restrict__ lp) {
    __shared__ __attribute__((aligned(16))) char smem[21504];
    _Float16* kbuf = (_Float16*)smem;            // 2 x 2048
    _Float16* vbuf = (_Float16*)(smem + 8192);   // 2 x 2048
    float* posl = (float*)(smem + 16384);        // 1024
    float* pbl = (float*)(smem + 20480);         // 256
    int h = blockIdx.x & 7;
    int jq = (blockIdx.x >> 3) & 3;
    int qb = blockIdx.x >> 5;
    int t = threadIdx.x, w = t >> 6, lane = t & 63, quad = lane >> 4, l16 = lane & 15;
    int q0 = qb * 128 + w * 32;
    float* opp = op + jq * 1048576;
    float* lpp = lp + jq * 32768;

    const _Float16* kg = ka + h * 131072 + jq * 32768;
    const _Float16* vg = va + h * 131072 + jq * 32768;

    // issue tile-0 async loads early; they land in kbuf/vbuf, drained by loop-top barrier
    gload_lds16(kg + (w * 64 + lane) * 8, kbuf + w * 512);
    gload_lds16(vg + (w * 64 + lane) * 8, vbuf + w * 512);

    // inline pos: stage pb head (256 f32), bilinear 16->64 for this j-quarter, x log2(e)
    pbl[t] = pb[h * 256 + t];
    __syncthreads();
    #pragma unroll
    for (int k = 0; k < 4; k++) {
        int j = jq * 1024 + t * 4 + k;
        int y = j >> 6, xx = j & 63;
        float sy = y * 0.25f - 0.375f, sx = xx * 0.25f - 0.375f;
        float fy = floorf(sy), fx = floorf(sx);
        float wy = sy - fy, wx = sx - fx;
        int y0 = (int)fy, x0 = (int)fx;
        int y1 = y0 + 1 < 15 ? y0 + 1 : 15;
        int x1 = x0 + 1 < 15 ? x0 + 1 : 15;
        y0 = y0 > 0 ? y0 : 0;
        x0 = x0 > 0 ? x0 : 0;
        float v = (1.f - wy) * ((1.f - wx) * pbl[y0 * 16 + x0] + wx * pbl[y0 * 16 + x1]) +
                  wy * ((1.f - wx) * pbl[y1 * 16 + x0] + wx * pbl[y1 * 16 + x1]);
        posl[t * 4 + k] = v * 1.4426950408889634f;
    }

    half8v qf0 = *(const half8v*)(qa + h * 131072 + (q0 + l16) * 32 + quad * 8);
    half8v qf1 = *(const half8v*)(qa + h * 131072 + (q0 + 16 + l16) * 32 + quad * 8);

    float4v o00 = {}, o01 = {}, o10 = {}, o11 = {};
    float lsum0 = 0.f, lsum1 = 0.f;
    const fp16v2 one2 = {(__fp16)1.0f, (__fp16)1.0f};

    for (int tile = 0; tile < 16; tile++) {
        int buf = tile & 1;
        __syncthreads();
        if (tile + 1 < 16) {
            gload_lds16(kg + (tile + 1) * 2048 + (w * 64 + lane) * 8,
                        kbuf + (buf ^ 1) * 2048 + w * 512);
            gload_lds16(vg + (tile + 1) * 2048 + (w * 64 + lane) * 8,
                        vbuf + (buf ^ 1) * 2048 + w * 512);
        }
        #pragma unroll
        for (int w16 = 0; w16 < 4; w16++) {
            half8v kf = *(const half8v*)(kbuf + buf * 2048 + w16 * 512 + lane * 8);
            half8v vf = *(const half8v*)(vbuf + buf * 2048 + w16 * 512 + lane * 8);
            float4v pbv = *(const float4v*)(posl + tile * 64 + w16 * 16 + quad * 4);

            float4v s0 = __builtin_amdgcn_mfma_f32_16x16x32_f16(kf, qf0, pbv, 0, 0, 0);
            float4v s1 = __builtin_amdgcn_mfma_f32_16x16x32_f16(kf, qf1, pbv, 0, 0, 0);

            float e0 = EXP2F(s0[0]);
            float e1 = EXP2F(s0[1]);
            float e2 = EXP2F(s0[2]);
            float e3 = EXP2F(s0[3]);
            float f0 = EXP2F(s1[0]);
            float f1 = EXP2F(s1[1]);
            float f2 = EXP2F(s1[2]);
            float f3 = EXP2F(s1[3]);

            fp16v2 a01 = __builtin_amdgcn_cvt_pkrtz(e0, e1);
            fp16v2 a23 = __builtin_amdgcn_cvt_pkrtz(e2, e3);
            fp16v2 b01 = __builtin_amdgcn_cvt_pkrtz(f0, f1);
            fp16v2 b23 = __builtin_amdgcn_cvt_pkrtz(f2, f3);
            half4v pa0 = __builtin_bit_cast(half4v, __builtin_shufflevector(a01, a23, 0, 1, 2, 3));
            half4v pa1 = __builtin_bit_cast(half4v, __builtin_shufflevector(b01, b23, 0, 1, 2, 3));

#if __has_builtin(__builtin_amdgcn_fdot2)
            lsum0 = __builtin_amdgcn_fdot2(a01, one2, lsum0, false);
            lsum0 = __builtin_amdgcn_fdot2(a23, one2, lsum0, false);
            lsum1 = __builtin_amdgcn_fdot2(b01, one2, lsum1, false);
            lsum1 = __builtin_amdgcn_fdot2(b23, one2, lsum1, false);
#else
            lsum0 += (e0 + e1) + (e2 + e3);
            lsum1 += (f0 + f1) + (f2 + f3);
#endif
            o00 = __builtin_amdgcn_mfma_f32_16x16x16f16(pa0, lo4(vf), o00, 0, 0, 0);
            o01 = __builtin_amdgcn_mfma_f32_16x16x16f16(pa0, hi4(vf), o01, 0, 0, 0);
            o10 = __builtin_amdgcn_mfma_f32_16x16x16f16(pa1, lo4(vf), o10, 0, 0, 0);
            o11 = __builtin_amdgcn_mfma_f32_16x16x16f16(pa1, hi4(vf), o11, 0, 0, 0);
        }
    }
    lsum0 += __shfl_xor(lsum0, 16, 64);
    lsum0 += __shfl_xor(lsum0, 32, 64);
    lsum1 += __shfl_xor(lsum1, 16, 64);
    lsum1 += __shfl_xor(lsum1, 32, 64);
    #pragma unroll
    for (int r = 0; r < 4; r++) {
        int qr = quad * 4 + r;
        int qi0 = q0 + qr, qi1 = q0 + 16 + qr;
        opp[qi0 * 256 + h * 32 + l16] = o00[r];
        opp[qi0 * 256 + h * 32 + 16 + l16] = o01[r];
        opp[qi1 * 256 + h * 32 + l16] = o10[r];
        opp[qi1 * 256 + h * 32 + 16 + l16] = o11[r];
    }
    if (quad == 0) {
        lpp[(q0 + l16) * 8 + h] = lsum0;
        lpp[(q0 + 16 + l16) * 8 + h] = lsum1;
    }
}

// ---------------- kernel 3: combine 4 partials + proj GEMM + residual + LayerNorm ------
__global__ __launch_bounds__(1024) void k_proj_ln(const _Float16* __restrict__ wph,
                                                  const float* __restrict__ op,
                                                  const float* __restrict__ lp,
                                                  const float* __restrict__ x,
                                                  const float* __restrict__ b_proj,
                                                  const float* __restrict__ gamma,
                                                  const float* __restrict__ beta,
                                                  float* __restrict__ out) {
    __shared__ __attribute__((aligned(16))) _Float16 ys[16 * 264];
    __shared__ float red[2][16][17];
    int p0 = blockIdx.x * 16;
    int t = threadIdx.x, w = t >> 6, lane = t & 63, quad = lane >> 4, l16 = lane & 15;
    {
        int p = t >> 6, cg = (t & 63) * 4;
        int pi = p0 + p;
        float4v a0 = *(const float4v*)(op + pi * 256 + cg);
        float4v a1 = *(const float4v*)(op + 1048576 + pi * 256 + cg);
        float4v a2 = *(const float4v*)(op + 2097152 + pi * 256 + cg);
        float4v a3 = *(const float4v*)(op + 3145728 + pi * 256 + cg);
        int hh = cg >> 5;
        float l = lp[pi * 8 + hh] + lp[32768 + pi * 8 + hh] +
                  lp[65536 + pi * 8 + hh] + lp[98304 + pi * 8 + hh];
        float inv = 1.f / l;
        half4v y;
        #pragma unroll
        for (int k = 0; k < 4; k++) y[k] = (_Float16)(((a0[k] + a1[k]) + (a2[k] + a3[k])) * inv);
        *(half4v*)(ys + p * 264 + cg) = y;
    }
    __syncthreads();
    float4v acc[2] = {};
    #pragma unroll
    for (int kc = 0; kc < 8; kc++) {
        half8v b = *(const half8v*)(ys + l16 * 264 + kc * 32 + quad * 8);
        #pragma unroll
        for (int mt = 0; mt < 2; mt++) {
            half8v a = *(const half8v*)(wph + (w * 32 + mt * 16 + l16) * 256 + kc * 32 + quad * 8);
            acc[mt] = __builtin_amdgcn_mfma_f32_16x16x32_f16(a, b, acc[mt], 0, 0, 0);
        }
    }
    int p = p0 + l16;
    float sum = 0.f, sumsq = 0.f;
    #pragma unroll
    for (int mt = 0; mt < 2; mt++)
        #pragma unroll
        for (int r = 0; r < 4; r++) {
            int c = w * 32 + mt * 16 + quad * 4 + r;
            float v = acc[mt][r] + b_proj[c] + x[c * HW + p];
            acc[mt][r] = v;
            sum += v;
            sumsq += v * v;
        }
    sum += __shfl_xor(sum, 16, 64);
    sum += __shfl_xor(sum, 32, 64);
    sumsq += __shfl_xor(sumsq, 16, 64);
    sumsq += __shfl_xor(sumsq, 32, 64);
    if (quad == 0) { red[0][w][l16] = sum; red[1][w][l16] = sumsq; }
    __syncthreads();
    float s0 = 0.f, s1 = 0.f;
    #pragma unroll
    for (int ww = 0; ww < 16; ww++) { s0 += red[0][ww][l16]; s1 += red[1][ww][l16]; }
    float mean = s0 * (1.f / 512.f);
    float var = s1 * (1.f / 512.f) - mean * mean;
    float rstd = rsqrtf(var + LN_EPS);
    #pragma unroll
    for (int mt = 0; mt < 2; mt++)
        #pragma unroll
        for (int r = 0; r < 4; r++) {
            int c = w * 32 + mt * 16 + quad * 4 + r;
            out[c * HW + p] = (acc[mt][r] - mean) * rstd * gamma[c] + beta[c];
        }
}

extern "C" void kernel_launch(void* const* d_in, const int* in_sizes, int n_in,
                              void* d_out, int out_size, void* d_ws, size_t ws_size,
                              hipStream_t stream) {
    const float* x      = (const float*)d_in[0];
    const float* w_qkv  = (const float*)d_in[1];
    const float* w_proj = (const float*)d_in[2];
    const float* b_proj = (const float*)d_in[3];
    const float* pos_b  = (const float*)d_in[4];
    const float* gamma  = (const float*)d_in[5];
    const float* beta   = (const float*)d_in[6];
    char* ws = (char*)d_ws;
    _Float16* qa  = (_Float16*)(ws);              // 2097152
    _Float16* ka  = (_Float16*)(ws + 2097152);    // 2097152
    _Float16* va  = (_Float16*)(ws + 4194304);    // 2097152
    float*    op  = (float*)   (ws + 6291456);    // 16777216
    float*    lp  = (float*)   (ws + 23068672);   // 524288
    _Float16* wph = (_Float16*)(ws + 23592960);   // 262144

    k_qkv<<<384, 256, 0, stream>>>(x, w_qkv, w_proj, wph, qa, ka, va);
    k_attn<<<1024, 256, 0, stream>>>(qa, ka, va, pos_b, op, lp);
    k_proj_ln<<<256, 1024, 0, stream>>>(wph, op, lp, x, b_proj, gamma, beta, (float*)d_out);
}